// Round 7
// baseline (877.079 us; speedup 1.0000x reference)
//
#include <hip/hip_runtime.h>
#include <hip/hip_bf16.h>
#include <math.h>

// Problem constants
#define B_   8
#define H_   8
#define S_   2048
#define D_   64      // head dim
#define BH_  64      // B*H
#define DPROJ_ 512

typedef __attribute__((ext_vector_type(8)))  _Float16 f16x8;
typedef __attribute__((ext_vector_type(4)))  float    f32x4;
typedef __attribute__((ext_vector_type(16))) float    f32x16;
typedef __attribute__((ext_vector_type(4)))  int      i32x4;

static __device__ __forceinline__ short f16bits(float f) {
    return __builtin_bit_cast(short, (_Float16)f);   // v_cvt_f16_f32 (RNE)
}

static __device__ __forceinline__ f16x8 load8_f32_f16(const float* p) {
    const float4 a = ((const float4*)p)[0];
    const float4 b = ((const float4*)p)[1];
    f16x8 r;
    r[0] = (_Float16)a.x; r[1] = (_Float16)a.y; r[2] = (_Float16)a.z; r[3] = (_Float16)a.w;
    r[4] = (_Float16)b.x; r[5] = (_Float16)b.y; r[6] = (_Float16)b.z; r[7] = (_Float16)b.w;
    return r;
}

// exp2: guarantee a single v_exp_f32 (HW computes 2^x)
#if __has_builtin(__builtin_amdgcn_exp2f)
#define EXP2(x) __builtin_amdgcn_exp2f(x)
#else
#define EXP2(x) exp2f(x)
#endif

// permlane32_swap: newA = {A_lo, B_lo}, newB = {A_hi, B_hi}.
static __device__ __forceinline__ void pl32swap(unsigned int& a, unsigned int& b) {
#if __has_builtin(__builtin_amdgcn_permlane32_swap)
    auto r = __builtin_amdgcn_permlane32_swap((int)a, (int)b, false, false);
    a = (unsigned int)r[0];
    b = (unsigned int)r[1];
#else
    const bool lh0 = ((threadIdx.x & 63) < 32);
    unsigned int xa = (unsigned int)__shfl_xor((int)a, 32);
    unsigned int xb = (unsigned int)__shfl_xor((int)b, 32);
    unsigned int na = lh0 ? a : xb;
    unsigned int nb = lh0 ? xa : b;
    a = na; b = nb;
#endif
}

// ---------------------------------------------------------------------------
// WORKSPACE LAYOUTS (fragment-major; unchanged from R12 — passed):
//   q_ws: [bh][s][64] f16, q pre-scaled by 0.1125*log2(e).
//   k_ws: [bh][T][h][lh][m32][8] f16  — wave reads frag h as one 1KB block.
//   v_ws: [bh][T][fg][lh][m32][8] f16 — same addressing structure.
// ---------------------------------------------------------------------------
#define QKST 520

__global__ __launch_bounds__(256)
void proj_kernel(const float* __restrict__ query, const float* __restrict__ key,
                 const float* __restrict__ value,
                 const float* __restrict__ Wq, const float* __restrict__ bq,
                 const float* __restrict__ Wk, const float* __restrict__ bk,
                 const float* __restrict__ Wv, const float* __restrict__ bv,
                 short* __restrict__ qws, short* __restrict__ kws,
                 short* __restrict__ vws)
{
    __shared__ __align__(16) short shbuf[16384];   // 32 KB, unioned per path

    const int tid  = threadIdx.x;
    const int wave = tid >> 6;
    const int lane = tid & 63;
    const int n    = lane & 15;
    const int quad = lane >> 4;
    const int kind = blockIdx.y;             // 0=q, 1=k, 2=v

    if (kind < 2) {
        short* tile = shbuf;                 // 16 x QKST = 16640 B
        const int r0   = blockIdx.x * 16;
        const int b    = r0 >> 11;
        const int s0   = r0 & 2047;
        // (1-dropout)/num_heads = 0.9/8 = 0.1125, times log2(e) for exp2 softmax
        const float QS = 0.16230319188537014f;

        const float* X    = kind ? key : query;
        const float* W    = kind ? Wk  : Wq;
        const float* bias = kind ? bk  : bq;
        short*       ows  = kind ? kws : qws;

        f16x8 af = load8_f32_f16(X + (r0 + n) * 32 + quad * 8);
        #pragma unroll
        for (int i = 0; i < 8; ++i) {
            const int c0 = wave * 128 + i * 16;
            f16x8 bfr = load8_f32_f16(W + (c0 + n) * 32 + quad * 8);
            f32x4 acc = {0.f, 0.f, 0.f, 0.f};
            acc = __builtin_amdgcn_mfma_f32_16x16x32_f16(af, bfr, acc, 0, 0, 0);
            const int c = c0 + n;
            const float bsf = bias[c];
            #pragma unroll
            for (int r = 0; r < 4; ++r) {
                float v = acc[r] + bsf;
                if (kind == 0) v *= QS;
                tile[(quad * 4 + r) * QKST + c] = f16bits(v);
            }
        }
        __syncthreads();

        #pragma unroll
        for (int k = 0; k < 4; ++k) {
            const int slot = k * 256 + tid;
            const int li   = slot & 7;          // d8 within head = h*2+lh
            const int chunk= slot >> 3;
            const int row  = chunk & 15;
            const int hd   = chunk >> 4;        // head 0..7
            uint4 vv = *(const uint4*)(tile + row * QKST + hd * 64 + li * 8);
            const int bh = b * 8 + hd;
            if (kind == 0) {
                *(uint4*)(ows + ((size_t)bh * S_ + s0 + row) * 64 + li * 8) = vv;
            } else {
                const int s = s0 + row;
                // k frag layout: bh*S*64 + T*2048 + li*256 + m32*8
                *(uint4*)(ows + (size_t)bh * (S_ * 64)
                              + (size_t)(s >> 5) * 2048 + li * 256 + (s & 31) * 8) = vv;
            }
        }
    } else {
        if (blockIdx.x >= 256) return;       // v path needs only 256 blocks
        short* vtile = shbuf;                // 2*256*32 shorts = 32768 B
        const int r0   = blockIdx.x * 64;
        const int b    = r0 >> 11;
        const int s0   = r0 & 2047;
        const int sub  = wave >> 1;
        const int sh   = (wave & 1) * 16;

        #pragma unroll
        for (int half = 0; half < 2; ++half) {
            const int cbh = half * 256;
            f16x8 bfr = load8_f32_f16(value + (r0 + sub * 32 + sh + n) * 32 + quad * 8);
            #pragma unroll
            for (int i = 0; i < 16; ++i) {
                const int c0 = cbh + i * 16;
                f16x8 af = load8_f32_f16(Wv + (c0 + n) * 32 + quad * 8);
                f32x4 acc = {0.f, 0.f, 0.f, 0.f};
                acc = __builtin_amdgcn_mfma_f32_16x16x32_f16(af, bfr, acc, 0, 0, 0);
                #pragma unroll
                for (int r = 0; r < 4; ++r) {
                    const int dc = c0 + quad * 4 + r;
                    float v = acc[r] + bv[dc];
                    vtile[(sub * 256 + (dc - cbh)) * 32 + sh + n] = f16bits(v);
                }
            }
            __syncthreads();

            #pragma unroll
            for (int k = 0; k < 8; ++k) {
                const int slot = k * 256 + tid;
                const int li   = slot & 3;          // k8 within tile (0..3)
                const int cl   = (slot >> 2) & 255;
                const int sb   = slot >> 10;
                const int c    = cbh + cl;
                const int bh   = b * 8 + (c >> 6);
                const int d    = c & 63;
                const int stile= (s0 >> 5) + sb;
                uint4 vv = *(const uint4*)(vtile + (sb * 256 + cl) * 32 + li * 8);
                // v frag layout: bh*S*64 + T*2048 + ((d>>5)*4+(li>>1)*2+(li&1))*256 + m32*8
                *(uint4*)(vws + (size_t)bh * (S_ * 64)
                              + (size_t)stile * 2048
                              + ((d >> 5) * 4 + (li >> 1) * 2 + (li & 1)) * 256
                              + (d & 31) * 8) = vv;
            }
            if (half == 0) __syncthreads();  // reuse vtile for second half
        }
    }
}

// ---------------------------------------------------------------------------
// Kernel 2: flash attention. R13: K-SPLIT OCCUPANCY (exact combine).
// R4/R5/R6 lesson: barriers, latency prefetch, and the entire LDS subsystem
// are all perf-neutral — the wall is the per-wave serial phase chain
// (QK MFMA -> 32x exp2 (1/4-rate trans) -> pack -> PV MFMA) with only
// 2 waves/SIMD to interleave phases across the matrix/trans/VALU pipes.
// Only VALU-work reduction ever moved the time (R2).
// Fix: 8-wave 512-thr blocks; wave w computes q-group (w&3) over K-HALF
// (w>>2) — 32 tiles each. 4096 waves -> 4 waves/SIMD (2x), with total
// VALU/MFMA/fragment-traffic UNCHANGED (this split only became possible
// once R12 removed LDS tile-sharing from the loop). Softmax is max-free
// unnormalized exp2, so partials combine EXACTLY: O = Oa + Ob, l = la + lb
// — one 33KB LDS exchange (two qg rounds) + epilogue on waves 0-3.
// launch_bounds(512,4) caps VGPR at 128 (loop body uses 112, unchanged).
// Retained: frag-major direct-global loads (8x contiguous 1KB per tile),
// A/B register ping-pong, XCD grid, exp2 softmax, permlane32_swap packing.
// ---------------------------------------------------------------------------
#define OTS 36   // epilogue LDS row stride (f32) for one 32-wide d-tile

static __device__ __forceinline__ void flash_compute(
    const f16x8 (&kf)[4], const f16x8 (&va)[4],
    const f16x8 (&qb)[2][4], const f32x16& z16,
    f32x16 (&o)[2][2], float (&pl)[2])
{
    #pragma unroll
    for (int qg = 0; qg < 2; ++qg) {
        f32x16 st = __builtin_amdgcn_mfma_f32_32x32x16_f16(kf[0], qb[qg][0], z16, 0, 0, 0);
        #pragma unroll
        for (int h = 1; h < 4; ++h)
            st = __builtin_amdgcn_mfma_f32_32x32x16_f16(kf[h], qb[qg][h], st, 0, 0, 0);

        float p[16];
        #pragma unroll
        for (int r = 0; r < 16; ++r) p[r] = EXP2(st[r]);
        float s01 = (p[0]+p[1]) + (p[2]+p[3]);
        float s23 = (p[4]+p[5]) + (p[6]+p[7]);
        float s45 = (p[8]+p[9]) + (p[10]+p[11]);
        float s67 = (p[12]+p[13]) + (p[14]+p[15]);
        pl[qg] += (s01 + s23) + (s45 + s67);

        unsigned int pk[8];
        #pragma unroll
        for (int i = 0; i < 8; ++i)
            pk[i] = __builtin_bit_cast(unsigned int,
                      __builtin_amdgcn_cvt_pkrtz(p[2 * i], p[2 * i + 1]));
        pl32swap(pk[0], pk[2]);
        pl32swap(pk[1], pk[3]);
        pl32swap(pk[4], pk[6]);
        pl32swap(pk[5], pk[7]);

        i32x4 bi0, bi1;
        bi0[0] = (int)pk[0]; bi0[1] = (int)pk[1];
        bi0[2] = (int)pk[2]; bi0[3] = (int)pk[3];
        bi1[0] = (int)pk[4]; bi1[1] = (int)pk[5];
        bi1[2] = (int)pk[6]; bi1[3] = (int)pk[7];
        f16x8 bf0 = __builtin_bit_cast(f16x8, bi0);
        f16x8 bf1 = __builtin_bit_cast(f16x8, bi1);

        #pragma unroll
        for (int t = 0; t < 2; ++t) {
            o[qg][t] = __builtin_amdgcn_mfma_f32_32x32x16_f16(va[t * 2 + 0], bf0, o[qg][t], 0, 0, 0);
            o[qg][t] = __builtin_amdgcn_mfma_f32_32x32x16_f16(va[t * 2 + 1], bf1, o[qg][t], 0, 0, 0);
        }
    }
}

__global__ __launch_bounds__(512, 4)
void flash_kernel(const short* __restrict__ qws, const short* __restrict__ kws,
                  const short* __restrict__ vws, float* __restrict__ out)
{
    // combine buffers (one qg round at a time) + separate epilogue buffer
    __shared__ float cb[4][2][16][64];                   // 32768 B
    __shared__ float cpl[4][64];                         //  1024 B
    __shared__ __align__(16) float olds[4 * 32 * OTS];   // 18432 B  (tot 52224)

    const int tid  = threadIdx.x;        // 0..511
    const int wave = tid >> 6;           // 0..7
    const int qw   = wave & 3;           // q-group
    const int kh2  = wave >> 2;          // k-half (0 or 1)
    const int lane = tid & 63;
    const int m32  = lane & 31;
    const int lh   = lane >> 5;          // lane-half
    const int koff = lh * 8;
    const int bh   = blockIdx.x;                     // XCD = bh % 8
    const int q0   = blockIdx.y * 256 + qw * 64;     // 64 q-rows per wave

    const short* qbase = qws + (size_t)bh * S_ * D_;
    const short* kfb   = kws + (size_t)bh * (S_ * 64);   // frag-major tiles
    const short* vfb   = vws + (size_t)bh * (S_ * 64);
    const int loff = lh * 256 + m32 * 8;                 // lane part of frag addr

    // Q^T B-frags (held): qb[qg][h]: B[d=h*16+lh*8+j][q=m32]
    f16x8 qb[2][4];
    #pragma unroll
    for (int qg = 0; qg < 2; ++qg)
        #pragma unroll
        for (int h = 0; h < 4; ++h)
            qb[qg][h] = *(const f16x8*)(qbase + (q0 + qg * 32 + m32) * D_ + h * 16 + koff);

    f32x16 z16;
    #pragma unroll
    for (int r = 0; r < 16; ++r) z16[r] = 0.f;

    f32x16 o[2][2];      // [qg][d-tile] O^T accumulators (partial: this k-half)
    float  pl[2] = {0.f, 0.f};
    #pragma unroll
    for (int qg = 0; qg < 2; ++qg)
        #pragma unroll
        for (int t = 0; t < 2; ++t)
            o[qg][t] = z16;

    // frag loads: 8 contiguous 1KB wave-loads per tile, direct from global
    #define LOADFRAGS(T, kf, va) do {                                        \
        const short* kp_ = kfb + (size_t)(T) * 2048 + loff;                  \
        const short* vp_ = vfb + (size_t)(T) * 2048 + loff;                  \
        kf[0] = *(const f16x8*)(kp_);                                        \
        kf[1] = *(const f16x8*)(kp_ + 512);                                  \
        kf[2] = *(const f16x8*)(kp_ + 1024);                                 \
        kf[3] = *(const f16x8*)(kp_ + 1536);                                 \
        va[0] = *(const f16x8*)(vp_);                                        \
        va[1] = *(const f16x8*)(vp_ + 512);                                  \
        va[2] = *(const f16x8*)(vp_ + 1024);                                 \
        va[3] = *(const f16x8*)(vp_ + 1536);                                 \
    } while (0)

    const int T0 = kh2 * 32;             // this wave's k-half: tiles T0..T0+31
    f16x8 kfA[4], vaA[4], kfB[4], vaB[4];
    LOADFRAGS(T0, kfA, vaA);

    for (int it = 0; it < 32; it += 2) {
        LOADFRAGS(T0 + it + 1, kfB, vaB);        // it+1 <= 31 always
        flash_compute(kfA, vaA, qb, z16, o, pl);
        if (it + 2 < 32)
            LOADFRAGS(T0 + it + 2, kfA, vaA);
        flash_compute(kfB, vaB, qb, z16, o, pl);
    }
    #undef LOADFRAGS

    // ---- exact k-half combine (unnormalized exp: partials just add) ----
    // two rounds (qg=0,1) through a 33KB buffer; all waves hit both barriers.
    #pragma unroll
    for (int qg = 0; qg < 2; ++qg) {
        if (wave >= 4) {
            const int u = wave - 4;
            #pragma unroll
            for (int t = 0; t < 2; ++t)
                #pragma unroll
                for (int r = 0; r < 16; ++r)
                    cb[u][t][r][lane] = o[qg][t][r];
            cpl[u][lane] = pl[qg];
        }
        __syncthreads();
        if (wave < 4) {
            #pragma unroll
            for (int t = 0; t < 2; ++t)
                #pragma unroll
                for (int r = 0; r < 16; ++r)
                    o[qg][t][r] += cb[wave][t][r][lane];
            pl[qg] += cpl[wave][lane];
        }
        __syncthreads();
    }

    if (wave >= 4) return;   // upper waves done (no barriers below)

    // epilogue (waves 0-3): complete row sums across lane-halves, normalize,
    // transpose O^T -> O per 32-wide d-tile through per-wave LDS, coalesced
    // f32x4 stores.
    const int b = bh >> 3, h = bh & 7;
    float* ow = olds + wave * (32 * OTS);
    #pragma unroll
    for (int qg = 0; qg < 2; ++qg) {
        float rs = pl[qg] + __shfl_xor(pl[qg], 32);
        float rl = 1.0f / rs;
        #pragma unroll
        for (int t = 0; t < 2; ++t) {
            const f32x16& ot = o[qg][t];
            #pragma unroll
            for (int g = 0; g < 4; ++g) {
                f32x4 w;
                w[0] = ot[g * 4 + 0] * rl;
                w[1] = ot[g * 4 + 1] * rl;
                w[2] = ot[g * 4 + 2] * rl;
                w[3] = ot[g * 4 + 3] * rl;
                // element (q=m32, dcol=r+8g+4lh) of this 32-wide d-tile
                *(f32x4*)(ow + m32 * OTS + 8 * g + 4 * lh) = w;
            }
            #pragma unroll
            for (int c = 0; c < 4; ++c) {
                const int row = (lane >> 3) + 8 * c;       // q-row within 32-row group
                f32x4 v = *(const f32x4*)(ow + row * OTS + (lane & 7) * 4);
                const int sq = q0 + qg * 32 + row;
                *(f32x4*)(out + ((size_t)(b * S_ + sq)) * DPROJ_
                              + h * 64 + t * 32 + (lane & 7) * 4) = v;
            }
        }
    }
}

// ---------------------------------------------------------------------------
extern "C" void kernel_launch(void* const* d_in, const int* in_sizes, int n_in,
                              void* d_out, int out_size, void* d_ws, size_t ws_size,
                              hipStream_t stream)
{
    const float* query = (const float*)d_in[0];
    const float* key   = (const float*)d_in[1];
    const float* value = (const float*)d_in[2];
    // d_in[3] = mask (int32) -- only its shape feeds the reference; unused.
    const float* Wq = (const float*)d_in[4];
    const float* bq = (const float*)d_in[5];
    const float* Wk = (const float*)d_in[6];
    const float* bk = (const float*)d_in[7];
    const float* Wv = (const float*)d_in[8];
    const float* bv = (const float*)d_in[9];

    float* out = (float*)d_out;
    short* ws  = (short*)d_ws;
    const size_t TSZ = (size_t)BH_ * S_ * D_;
    short* qws = ws;
    short* kws = ws + TSZ;
    short* vws = ws + 2 * TSZ;

    proj_kernel<<<dim3((B_ * S_) / 16, 3), 256, 0, stream>>>(
        query, key, value, Wq, bq, Wk, bk, Wv, bv, qws, kws, vws);
    flash_kernel<<<dim3(BH_, S_ / 256), 512, 0, stream>>>(qws, kws, vws, out);
}

// Round 8
// 191.313 us; speedup vs baseline: 4.5845x; 4.5845x over previous
//
#include <hip/hip_runtime.h>
#include <hip/hip_bf16.h>
#include <math.h>

// Problem constants
#define B_   8
#define H_   8
#define S_   2048
#define D_   64      // head dim
#define BH_  64      // B*H
#define DPROJ_ 512

typedef __attribute__((ext_vector_type(8)))  _Float16 f16x8;
typedef __attribute__((ext_vector_type(4)))  float    f32x4;
typedef __attribute__((ext_vector_type(16))) float    f32x16;
typedef __attribute__((ext_vector_type(4)))  int      i32x4;

static __device__ __forceinline__ short f16bits(float f) {
    return __builtin_bit_cast(short, (_Float16)f);   // v_cvt_f16_f32 (RNE)
}

static __device__ __forceinline__ f16x8 load8_f32_f16(const float* p) {
    const float4 a = ((const float4*)p)[0];
    const float4 b = ((const float4*)p)[1];
    f16x8 r;
    r[0] = (_Float16)a.x; r[1] = (_Float16)a.y; r[2] = (_Float16)a.z; r[3] = (_Float16)a.w;
    r[4] = (_Float16)b.x; r[5] = (_Float16)b.y; r[6] = (_Float16)b.z; r[7] = (_Float16)b.w;
    return r;
}

// exp2: guarantee a single v_exp_f32 (HW computes 2^x)
#if __has_builtin(__builtin_amdgcn_exp2f)
#define EXP2(x) __builtin_amdgcn_exp2f(x)
#else
#define EXP2(x) exp2f(x)
#endif

// permlane32_swap: newA = {A_lo, B_lo}, newB = {A_hi, B_hi}.
static __device__ __forceinline__ void pl32swap(unsigned int& a, unsigned int& b) {
#if __has_builtin(__builtin_amdgcn_permlane32_swap)
    auto r = __builtin_amdgcn_permlane32_swap((int)a, (int)b, false, false);
    a = (unsigned int)r[0];
    b = (unsigned int)r[1];
#else
    const bool lh0 = ((threadIdx.x & 63) < 32);
    unsigned int xa = (unsigned int)__shfl_xor((int)a, 32);
    unsigned int xb = (unsigned int)__shfl_xor((int)b, 32);
    unsigned int na = lh0 ? a : xb;
    unsigned int nb = lh0 ? xa : b;
    a = na; b = nb;
#endif
}

// ---------------------------------------------------------------------------
// WORKSPACE LAYOUTS (fragment-major; unchanged from R12 — passed):
//   q_ws: [bh][s][64] f16, q pre-scaled by 0.1125*log2(e).
//   k_ws: [bh][T][h][lh][m32][8] f16  — wave reads frag h as one 1KB block.
//   v_ws: [bh][T][fg][lh][m32][8] f16 — same addressing structure.
// ---------------------------------------------------------------------------
#define QKST 520

__global__ __launch_bounds__(256)
void proj_kernel(const float* __restrict__ query, const float* __restrict__ key,
                 const float* __restrict__ value,
                 const float* __restrict__ Wq, const float* __restrict__ bq,
                 const float* __restrict__ Wk, const float* __restrict__ bk,
                 const float* __restrict__ Wv, const float* __restrict__ bv,
                 short* __restrict__ qws, short* __restrict__ kws,
                 short* __restrict__ vws)
{
    __shared__ __align__(16) short shbuf[16384];   // 32 KB, unioned per path

    const int tid  = threadIdx.x;
    const int wave = tid >> 6;
    const int lane = tid & 63;
    const int n    = lane & 15;
    const int quad = lane >> 4;
    const int kind = blockIdx.y;             // 0=q, 1=k, 2=v

    if (kind < 2) {
        short* tile = shbuf;                 // 16 x QKST = 16640 B
        const int r0   = blockIdx.x * 16;
        const int b    = r0 >> 11;
        const int s0   = r0 & 2047;
        // (1-dropout)/num_heads = 0.9/8 = 0.1125, times log2(e) for exp2 softmax
        const float QS = 0.16230319188537014f;

        const float* X    = kind ? key : query;
        const float* W    = kind ? Wk  : Wq;
        const float* bias = kind ? bk  : bq;
        short*       ows  = kind ? kws : qws;

        f16x8 af = load8_f32_f16(X + (r0 + n) * 32 + quad * 8);
        #pragma unroll
        for (int i = 0; i < 8; ++i) {
            const int c0 = wave * 128 + i * 16;
            f16x8 bfr = load8_f32_f16(W + (c0 + n) * 32 + quad * 8);
            f32x4 acc = {0.f, 0.f, 0.f, 0.f};
            acc = __builtin_amdgcn_mfma_f32_16x16x32_f16(af, bfr, acc, 0, 0, 0);
            const int c = c0 + n;
            const float bsf = bias[c];
            #pragma unroll
            for (int r = 0; r < 4; ++r) {
                float v = acc[r] + bsf;
                if (kind == 0) v *= QS;
                tile[(quad * 4 + r) * QKST + c] = f16bits(v);
            }
        }
        __syncthreads();

        #pragma unroll
        for (int k = 0; k < 4; ++k) {
            const int slot = k * 256 + tid;
            const int li   = slot & 7;          // d8 within head = h*2+lh
            const int chunk= slot >> 3;
            const int row  = chunk & 15;
            const int hd   = chunk >> 4;        // head 0..7
            uint4 vv = *(const uint4*)(tile + row * QKST + hd * 64 + li * 8);
            const int bh = b * 8 + hd;
            if (kind == 0) {
                *(uint4*)(ows + ((size_t)bh * S_ + s0 + row) * 64 + li * 8) = vv;
            } else {
                const int s = s0 + row;
                // k frag layout: bh*S*64 + T*2048 + li*256 + m32*8
                *(uint4*)(ows + (size_t)bh * (S_ * 64)
                              + (size_t)(s >> 5) * 2048 + li * 256 + (s & 31) * 8) = vv;
            }
        }
    } else {
        if (blockIdx.x >= 256) return;       // v path needs only 256 blocks
        short* vtile = shbuf;                // 2*256*32 shorts = 32768 B
        const int r0   = blockIdx.x * 64;
        const int b    = r0 >> 11;
        const int s0   = r0 & 2047;
        const int sub  = wave >> 1;
        const int sh   = (wave & 1) * 16;

        #pragma unroll
        for (int half = 0; half < 2; ++half) {
            const int cbh = half * 256;
            f16x8 bfr = load8_f32_f16(value + (r0 + sub * 32 + sh + n) * 32 + quad * 8);
            #pragma unroll
            for (int i = 0; i < 16; ++i) {
                const int c0 = cbh + i * 16;
                f16x8 af = load8_f32_f16(Wv + (c0 + n) * 32 + quad * 8);
                f32x4 acc = {0.f, 0.f, 0.f, 0.f};
                acc = __builtin_amdgcn_mfma_f32_16x16x32_f16(af, bfr, acc, 0, 0, 0);
                #pragma unroll
                for (int r = 0; r < 4; ++r) {
                    const int dc = c0 + quad * 4 + r;
                    float v = acc[r] + bv[dc];
                    vtile[(sub * 256 + (dc - cbh)) * 32 + sh + n] = f16bits(v);
                }
            }
            __syncthreads();

            #pragma unroll
            for (int k = 0; k < 8; ++k) {
                const int slot = k * 256 + tid;
                const int li   = slot & 3;          // k8 within tile (0..3)
                const int cl   = (slot >> 2) & 255;
                const int sb   = slot >> 10;
                const int c    = cbh + cl;
                const int bh   = b * 8 + (c >> 6);
                const int d    = c & 63;
                const int stile= (s0 >> 5) + sb;
                uint4 vv = *(const uint4*)(vtile + (sb * 256 + cl) * 32 + li * 8);
                // v frag layout: bh*S*64 + T*2048 + ((d>>5)*4+(li>>1)*2+(li&1))*256 + m32*8
                *(uint4*)(vws + (size_t)bh * (S_ * 64)
                              + (size_t)stile * 2048
                              + ((d >> 5) * 4 + (li >> 1) * 2 + (li & 1)) * 256
                              + (d & 31) * 8) = vv;
            }
            if (half == 0) __syncthreads();  // reuse vtile for second half
        }
    }
}

// ---------------------------------------------------------------------------
// Kernel 2: flash attention. R14: INTRA-WAVE TWO-TILE PIPELINE (T15).
// R7 lesson: K-split spilled (VGPR 64, 3.7GB scratch traffic) — occupancy
// is HARD-CAPPED at 2 waves/SIMD by the 176-reg loop state; launch_bounds
// 2nd arg behaves as blocks/CU here (R1's 64-reg cap, same trap).
// Surviving facts: barriers free (R4), load latency free (R5), LDS free
// (R6), occupancy unreachable (R1/R3/R7). The wall is the per-tile serial
// phase chain (QKx4 dep MFMA -> 32 exp2 -> pack -> PV) with only 2 waves/
// SIMD to interleave pipes.
// Fix: keep TWO tiles' score state live (stA/stB, +32 VGPR) and issue tile
// t+1's QK MFMAs (matrix pipe, independent) textually BEFORE tile t's
// exp/pack/PV (trans/VALU pipe): each wave feeds both pipes itself.
// K-frag loads hoisted a full finish-phase ahead; V-frag loads land right
// after the finish that frees their slot. Steady-state loop (it<62) is
// branch-free; tiles 62/63 peeled. ~240 unified regs: fits 2 waves/SIMD
// (<=256), NO spill (verify: VGPR_Count >= 200, hbm_bytes ~62MB).
// Retained: R6 frag-major direct-global loads, 4 waves x 64 q-rows,
// grid (BH, S/256), exp2 softmax, permlane32_swap packing, no loop LDS.
// ---------------------------------------------------------------------------
#define OTS 36   // epilogue LDS row stride (f32) for one 32-wide d-tile

// QK phase: 8 MFMAs (two independent chains of 4) -> st[2]
static __device__ __forceinline__ void qk_phase(
    const f16x8 (&kf)[4], const f16x8 (&qb)[2][4], const f32x16& z16,
    f32x16 (&st)[2])
{
    #pragma unroll
    for (int qg = 0; qg < 2; ++qg) {
        st[qg] = __builtin_amdgcn_mfma_f32_32x32x16_f16(kf[0], qb[qg][0], z16, 0, 0, 0);
        #pragma unroll
        for (int h = 1; h < 4; ++h)
            st[qg] = __builtin_amdgcn_mfma_f32_32x32x16_f16(kf[h], qb[qg][h], st[qg], 0, 0, 0);
    }
}

// Finish phase: exp2 (in place), row-sum, pack, PV accumulate.
static __device__ __forceinline__ void finish_phase(
    f32x16 (&st)[2], const f16x8 (&va)[4],
    f32x16 (&o)[2][2], float (&pl)[2])
{
    #pragma unroll
    for (int qg = 0; qg < 2; ++qg) {
        #pragma unroll
        for (int r = 0; r < 16; ++r) st[qg][r] = EXP2(st[qg][r]);
        float s01 = (st[qg][0]+st[qg][1]) + (st[qg][2]+st[qg][3]);
        float s23 = (st[qg][4]+st[qg][5]) + (st[qg][6]+st[qg][7]);
        float s45 = (st[qg][8]+st[qg][9]) + (st[qg][10]+st[qg][11]);
        float s67 = (st[qg][12]+st[qg][13]) + (st[qg][14]+st[qg][15]);
        pl[qg] += (s01 + s23) + (s45 + s67);

        unsigned int pk[8];
        #pragma unroll
        for (int i = 0; i < 8; ++i)
            pk[i] = __builtin_bit_cast(unsigned int,
                      __builtin_amdgcn_cvt_pkrtz(st[qg][2 * i], st[qg][2 * i + 1]));
        pl32swap(pk[0], pk[2]);
        pl32swap(pk[1], pk[3]);
        pl32swap(pk[4], pk[6]);
        pl32swap(pk[5], pk[7]);

        i32x4 bi0, bi1;
        bi0[0] = (int)pk[0]; bi0[1] = (int)pk[1];
        bi0[2] = (int)pk[2]; bi0[3] = (int)pk[3];
        bi1[0] = (int)pk[4]; bi1[1] = (int)pk[5];
        bi1[2] = (int)pk[6]; bi1[3] = (int)pk[7];
        f16x8 bf0 = __builtin_bit_cast(f16x8, bi0);
        f16x8 bf1 = __builtin_bit_cast(f16x8, bi1);

        #pragma unroll
        for (int t = 0; t < 2; ++t) {
            o[qg][t] = __builtin_amdgcn_mfma_f32_32x32x16_f16(va[t * 2 + 0], bf0, o[qg][t], 0, 0, 0);
            o[qg][t] = __builtin_amdgcn_mfma_f32_32x32x16_f16(va[t * 2 + 1], bf1, o[qg][t], 0, 0, 0);
        }
    }
}

__global__ __launch_bounds__(256, 2)
void flash_kernel(const short* __restrict__ qws, const short* __restrict__ kws,
                  const short* __restrict__ vws, float* __restrict__ out)
{
    __shared__ __align__(16) float olds[4 * 32 * OTS];   // 18432 B (epilogue only)

    const int tid  = threadIdx.x;
    const int wave = tid >> 6;
    const int lane = tid & 63;
    const int m32  = lane & 31;
    const int lh   = lane >> 5;          // lane-half
    const int koff = lh * 8;
    const int bh   = blockIdx.x;                     // XCD = bh % 8
    const int q0   = blockIdx.y * 256 + wave * 64;   // 64 q-rows per wave

    const short* qbase = qws + (size_t)bh * S_ * D_;
    const short* kfb   = kws + (size_t)bh * (S_ * 64);   // frag-major tiles
    const short* vfb   = vws + (size_t)bh * (S_ * 64);
    const int loff = lh * 256 + m32 * 8;                 // lane part of frag addr

    // Q^T B-frags (held): qb[qg][h]: B[d=h*16+lh*8+j][q=m32]
    f16x8 qb[2][4];
    #pragma unroll
    for (int qg = 0; qg < 2; ++qg)
        #pragma unroll
        for (int h = 0; h < 4; ++h)
            qb[qg][h] = *(const f16x8*)(qbase + (q0 + qg * 32 + m32) * D_ + h * 16 + koff);

    f32x16 z16;
    #pragma unroll
    for (int r = 0; r < 16; ++r) z16[r] = 0.f;

    f32x16 o[2][2];      // [qg][d-tile] O^T accumulators
    float  pl[2] = {0.f, 0.f};
    #pragma unroll
    for (int qg = 0; qg < 2; ++qg)
        #pragma unroll
        for (int t = 0; t < 2; ++t)
            o[qg][t] = z16;

    #define LOADK(T, kf) do {                                                \
        const short* kp_ = kfb + (size_t)(T) * 2048 + loff;                  \
        kf[0] = *(const f16x8*)(kp_);                                        \
        kf[1] = *(const f16x8*)(kp_ + 512);                                  \
        kf[2] = *(const f16x8*)(kp_ + 1024);                                 \
        kf[3] = *(const f16x8*)(kp_ + 1536);                                 \
    } while (0)
    #define LOADV(T, va) do {                                                \
        const short* vp_ = vfb + (size_t)(T) * 2048 + loff;                  \
        va[0] = *(const f16x8*)(vp_);                                        \
        va[1] = *(const f16x8*)(vp_ + 512);                                  \
        va[2] = *(const f16x8*)(vp_ + 1024);                                 \
        va[3] = *(const f16x8*)(vp_ + 1536);                                 \
    } while (0)

    f16x8 kfA[4], vaA[4], kfB[4], vaB[4];
    f32x16 stA[2], stB[2];

    // prologue: frags for tiles 0,1; scores for tile 0
    LOADK(0, kfA);  LOADV(0, vaA);
    LOADK(1, kfB);  LOADV(1, vaB);
    qk_phase(kfA, qb, z16, stA);         // tile 0

    // steady state: finish tile t while QK of tile t+1 issues.
    // Invariant at loop head: stA=scores(it), vaA=V(it), kfB/vaB=frags(it+1).
    for (int it = 0; it < 62; it += 2) {
        qk_phase(kfB, qb, z16, stB);     // tile it+1 (matrix pipe, indep)
        LOADK(it + 2, kfA);              // kfA free since tile it's QK
        finish_phase(stA, vaA, o, pl);   // tile it (trans/VALU + PV)
        LOADV(it + 2, vaA);              // vaA freed by finish above

        qk_phase(kfA, qb, z16, stA);     // tile it+2
        LOADK(it + 3, kfB);
        finish_phase(stB, vaB, o, pl);   // tile it+1
        LOADV(it + 3, vaB);
    }
    // tail: stA=scores(62), vaA=V(62), kfB/vaB=frags(63)
    qk_phase(kfB, qb, z16, stB);         // tile 63
    finish_phase(stA, vaA, o, pl);       // tile 62
    finish_phase(stB, vaB, o, pl);       // tile 63

    #undef LOADK
    #undef LOADV

    // epilogue: complete row sums across lane-halves, normalize, transpose
    // O^T -> O one 32-wide d-tile at a time through per-wave LDS (32x36 f32,
    // per-wave region — no cross-wave hazard, no barrier), coalesced stores.
    const int b = bh >> 3, h = bh & 7;
    float* ow = olds + wave * (32 * OTS);
    #pragma unroll
    for (int qg = 0; qg < 2; ++qg) {
        float rs = pl[qg] + __shfl_xor(pl[qg], 32);
        float rl = 1.0f / rs;
        #pragma unroll
        for (int t = 0; t < 2; ++t) {
            const f32x16& ot = o[qg][t];
            #pragma unroll
            for (int g = 0; g < 4; ++g) {
                f32x4 w;
                w[0] = ot[g * 4 + 0] * rl;
                w[1] = ot[g * 4 + 1] * rl;
                w[2] = ot[g * 4 + 2] * rl;
                w[3] = ot[g * 4 + 3] * rl;
                // element (q=m32, dcol=r+8g+4lh) of this 32-wide d-tile
                *(f32x4*)(ow + m32 * OTS + 8 * g + 4 * lh) = w;
            }
            #pragma unroll
            for (int c = 0; c < 4; ++c) {
                const int row = (lane >> 3) + 8 * c;       // q-row within 32-row group
                f32x4 v = *(const f32x4*)(ow + row * OTS + (lane & 7) * 4);
                const int sq = q0 + qg * 32 + row;
                *(f32x4*)(out + ((size_t)(b * S_ + sq)) * DPROJ_
                              + h * 64 + t * 32 + (lane & 7) * 4) = v;
            }
        }
    }
}

// ---------------------------------------------------------------------------
extern "C" void kernel_launch(void* const* d_in, const int* in_sizes, int n_in,
                              void* d_out, int out_size, void* d_ws, size_t ws_size,
                              hipStream_t stream)
{
    const float* query = (const float*)d_in[0];
    const float* key   = (const float*)d_in[1];
    const float* value = (const float*)d_in[2];
    // d_in[3] = mask (int32) -- only its shape feeds the reference; unused.
    const float* Wq = (const float*)d_in[4];
    const float* bq = (const float*)d_in[5];
    const float* Wk = (const float*)d_in[6];
    const float* bk = (const float*)d_in[7];
    const float* Wv = (const float*)d_in[8];
    const float* bv = (const float*)d_in[9];

    float* out = (float*)d_out;
    short* ws  = (short*)d_ws;
    const size_t TSZ = (size_t)BH_ * S_ * D_;
    short* qws = ws;
    short* kws = ws + TSZ;
    short* vws = ws + 2 * TSZ;

    proj_kernel<<<dim3((B_ * S_) / 16, 3), 256, 0, stream>>>(
        query, key, value, Wq, bq, Wk, bk, Wv, bv, qws, kws, vws);
    flash_kernel<<<dim3(BH_, S_ / 256), 256, 0, stream>>>(qws, kws, vws, out);
}

// Round 9
// 186.028 us; speedup vs baseline: 4.7148x; 1.0284x over previous
//
#include <hip/hip_runtime.h>
#include <hip/hip_bf16.h>
#include <math.h>

// Problem constants
#define B_   8
#define H_   8
#define S_   2048
#define D_   64      // head dim
#define BH_  64      // B*H
#define DPROJ_ 512

typedef __attribute__((ext_vector_type(8)))  _Float16 f16x8;
typedef __attribute__((ext_vector_type(4)))  float    f32x4;
typedef __attribute__((ext_vector_type(16))) float    f32x16;
typedef __attribute__((ext_vector_type(4)))  int      i32x4;

static __device__ __forceinline__ short f16bits(float f) {
    return __builtin_bit_cast(short, (_Float16)f);   // v_cvt_f16_f32 (RNE)
}

static __device__ __forceinline__ f16x8 load8_f32_f16(const float* p) {
    const float4 a = ((const float4*)p)[0];
    const float4 b = ((const float4*)p)[1];
    f16x8 r;
    r[0] = (_Float16)a.x; r[1] = (_Float16)a.y; r[2] = (_Float16)a.z; r[3] = (_Float16)a.w;
    r[4] = (_Float16)b.x; r[5] = (_Float16)b.y; r[6] = (_Float16)b.z; r[7] = (_Float16)b.w;
    return r;
}

// exp2: guarantee a single v_exp_f32 (HW computes 2^x)
#if __has_builtin(__builtin_amdgcn_exp2f)
#define EXP2(x) __builtin_amdgcn_exp2f(x)
#else
#define EXP2(x) exp2f(x)
#endif

// permlane32_swap: newA = {A_lo, B_lo}, newB = {A_hi, B_hi}.
static __device__ __forceinline__ void pl32swap(unsigned int& a, unsigned int& b) {
#if __has_builtin(__builtin_amdgcn_permlane32_swap)
    auto r = __builtin_amdgcn_permlane32_swap((int)a, (int)b, false, false);
    a = (unsigned int)r[0];
    b = (unsigned int)r[1];
#else
    const bool lh0 = ((threadIdx.x & 63) < 32);
    unsigned int xa = (unsigned int)__shfl_xor((int)a, 32);
    unsigned int xb = (unsigned int)__shfl_xor((int)b, 32);
    unsigned int na = lh0 ? a : xb;
    unsigned int nb = lh0 ? xa : b;
    a = na; b = nb;
#endif
}

// ---------------------------------------------------------------------------
// WORKSPACE LAYOUTS (fragment-major; unchanged from R12 — passed):
//   q_ws: [bh][s][64] f16, q pre-scaled by 0.1125*log2(e).
//   k_ws: [bh][T][h][lh][m32][8] f16  — wave reads frag h as one 1KB block.
//   v_ws: [bh][T][fg][lh][m32][8] f16 — same addressing structure.
// ---------------------------------------------------------------------------
#define QKST 520

__global__ __launch_bounds__(256)
void proj_kernel(const float* __restrict__ query, const float* __restrict__ key,
                 const float* __restrict__ value,
                 const float* __restrict__ Wq, const float* __restrict__ bq,
                 const float* __restrict__ Wk, const float* __restrict__ bk,
                 const float* __restrict__ Wv, const float* __restrict__ bv,
                 short* __restrict__ qws, short* __restrict__ kws,
                 short* __restrict__ vws)
{
    __shared__ __align__(16) short shbuf[16384];   // 32 KB, unioned per path

    const int tid  = threadIdx.x;
    const int wave = tid >> 6;
    const int lane = tid & 63;
    const int n    = lane & 15;
    const int quad = lane >> 4;
    const int kind = blockIdx.y;             // 0=q, 1=k, 2=v

    if (kind < 2) {
        short* tile = shbuf;                 // 16 x QKST = 16640 B
        const int r0   = blockIdx.x * 16;
        const int b    = r0 >> 11;
        const int s0   = r0 & 2047;
        // (1-dropout)/num_heads = 0.9/8 = 0.1125, times log2(e) for exp2 softmax
        const float QS = 0.16230319188537014f;

        const float* X    = kind ? key : query;
        const float* W    = kind ? Wk  : Wq;
        const float* bias = kind ? bk  : bq;
        short*       ows  = kind ? kws : qws;

        f16x8 af = load8_f32_f16(X + (r0 + n) * 32 + quad * 8);
        #pragma unroll
        for (int i = 0; i < 8; ++i) {
            const int c0 = wave * 128 + i * 16;
            f16x8 bfr = load8_f32_f16(W + (c0 + n) * 32 + quad * 8);
            f32x4 acc = {0.f, 0.f, 0.f, 0.f};
            acc = __builtin_amdgcn_mfma_f32_16x16x32_f16(af, bfr, acc, 0, 0, 0);
            const int c = c0 + n;
            const float bsf = bias[c];
            #pragma unroll
            for (int r = 0; r < 4; ++r) {
                float v = acc[r] + bsf;
                if (kind == 0) v *= QS;
                tile[(quad * 4 + r) * QKST + c] = f16bits(v);
            }
        }
        __syncthreads();

        #pragma unroll
        for (int k = 0; k < 4; ++k) {
            const int slot = k * 256 + tid;
            const int li   = slot & 7;          // d8 within head = h*2+lh
            const int chunk= slot >> 3;
            const int row  = chunk & 15;
            const int hd   = chunk >> 4;        // head 0..7
            uint4 vv = *(const uint4*)(tile + row * QKST + hd * 64 + li * 8);
            const int bh = b * 8 + hd;
            if (kind == 0) {
                *(uint4*)(ows + ((size_t)bh * S_ + s0 + row) * 64 + li * 8) = vv;
            } else {
                const int s = s0 + row;
                // k frag layout: bh*S*64 + T*2048 + li*256 + m32*8
                *(uint4*)(ows + (size_t)bh * (S_ * 64)
                              + (size_t)(s >> 5) * 2048 + li * 256 + (s & 31) * 8) = vv;
            }
        }
    } else {
        if (blockIdx.x >= 256) return;       // v path needs only 256 blocks
        short* vtile = shbuf;                // 2*256*32 shorts = 32768 B
        const int r0   = blockIdx.x * 64;
        const int b    = r0 >> 11;
        const int s0   = r0 & 2047;
        const int sub  = wave >> 1;
        const int sh   = (wave & 1) * 16;

        #pragma unroll
        for (int half = 0; half < 2; ++half) {
            const int cbh = half * 256;
            f16x8 bfr = load8_f32_f16(value + (r0 + sub * 32 + sh + n) * 32 + quad * 8);
            #pragma unroll
            for (int i = 0; i < 16; ++i) {
                const int c0 = cbh + i * 16;
                f16x8 af = load8_f32_f16(Wv + (c0 + n) * 32 + quad * 8);
                f32x4 acc = {0.f, 0.f, 0.f, 0.f};
                acc = __builtin_amdgcn_mfma_f32_16x16x32_f16(af, bfr, acc, 0, 0, 0);
                #pragma unroll
                for (int r = 0; r < 4; ++r) {
                    const int dc = c0 + quad * 4 + r;
                    float v = acc[r] + bv[dc];
                    vtile[(sub * 256 + (dc - cbh)) * 32 + sh + n] = f16bits(v);
                }
            }
            __syncthreads();

            #pragma unroll
            for (int k = 0; k < 8; ++k) {
                const int slot = k * 256 + tid;
                const int li   = slot & 3;          // k8 within tile (0..3)
                const int cl   = (slot >> 2) & 255;
                const int sb   = slot >> 10;
                const int c    = cbh + cl;
                const int bh   = b * 8 + (c >> 6);
                const int d    = c & 63;
                const int stile= (s0 >> 5) + sb;
                uint4 vv = *(const uint4*)(vtile + (sb * 256 + cl) * 32 + li * 8);
                // v frag layout: bh*S*64 + T*2048 + ((d>>5)*4+(li>>1)*2+(li&1))*256 + m32*8
                *(uint4*)(vws + (size_t)bh * (S_ * 64)
                              + (size_t)stile * 2048
                              + ((d >> 5) * 4 + (li >> 1) * 2 + (li & 1)) * 256
                              + (d & 31) * 8) = vv;
            }
            if (half == 0) __syncthreads();  // reuse vtile for second half
        }
    }
}

// ---------------------------------------------------------------------------
// Kernel 2: flash attention. R15 = R12/R6 structure (82.6 us, VGPR 112,
// no spill) + T5 s_setprio around the MFMA clusters.
// R8 lesson: a second live score-state forces accvgpr moves (+8% VALU) +
// spill — T15 does not pay here (matches guide m253). Reverted.
// Evidence ledger: barriers free (R4), load latency free (R5), LDS free
// (R6), occupancy reg-capped at 2 waves/SIMD (R7), intra-wave 2-tile
// pipeline negative (R8). Structure pinned ~82 us, MFMA 37% + VALU 40%.
// T5 mechanism (guide m191, +4-7% attn): waves here are barrier-free and
// phase-drifted; setprio(1) during a wave's MFMA cluster makes the SIMD
// scheduler prefer matrix-issue over the co-resident wave's exp/pack
// stream, improving phase mixing that source order cannot express.
// Zero registers, zero hazard. Pre-commit: if |delta| <= 1.5%, structure
// is at its ceiling -> ROOFLINE next round.
// ---------------------------------------------------------------------------
#define OTS 36   // epilogue LDS row stride (f32) for one 32-wide d-tile

static __device__ __forceinline__ void flash_compute(
    const f16x8 (&kf)[4], const f16x8 (&va)[4],
    const f16x8 (&qb)[2][4], const f32x16& z16,
    f32x16 (&o)[2][2], float (&pl)[2])
{
    #pragma unroll
    for (int qg = 0; qg < 2; ++qg) {
        __builtin_amdgcn_s_setprio(1);
        f32x16 st = __builtin_amdgcn_mfma_f32_32x32x16_f16(kf[0], qb[qg][0], z16, 0, 0, 0);
        #pragma unroll
        for (int h = 1; h < 4; ++h)
            st = __builtin_amdgcn_mfma_f32_32x32x16_f16(kf[h], qb[qg][h], st, 0, 0, 0);
        __builtin_amdgcn_s_setprio(0);

        float p[16];
        #pragma unroll
        for (int r = 0; r < 16; ++r) p[r] = EXP2(st[r]);
        float s01 = (p[0]+p[1]) + (p[2]+p[3]);
        float s23 = (p[4]+p[5]) + (p[6]+p[7]);
        float s45 = (p[8]+p[9]) + (p[10]+p[11]);
        float s67 = (p[12]+p[13]) + (p[14]+p[15]);
        pl[qg] += (s01 + s23) + (s45 + s67);

        unsigned int pk[8];
        #pragma unroll
        for (int i = 0; i < 8; ++i)
            pk[i] = __builtin_bit_cast(unsigned int,
                      __builtin_amdgcn_cvt_pkrtz(p[2 * i], p[2 * i + 1]));
        pl32swap(pk[0], pk[2]);
        pl32swap(pk[1], pk[3]);
        pl32swap(pk[4], pk[6]);
        pl32swap(pk[5], pk[7]);

        i32x4 bi0, bi1;
        bi0[0] = (int)pk[0]; bi0[1] = (int)pk[1];
        bi0[2] = (int)pk[2]; bi0[3] = (int)pk[3];
        bi1[0] = (int)pk[4]; bi1[1] = (int)pk[5];
        bi1[2] = (int)pk[6]; bi1[3] = (int)pk[7];
        f16x8 bf0 = __builtin_bit_cast(f16x8, bi0);
        f16x8 bf1 = __builtin_bit_cast(f16x8, bi1);

        __builtin_amdgcn_s_setprio(1);
        #pragma unroll
        for (int t = 0; t < 2; ++t) {
            o[qg][t] = __builtin_amdgcn_mfma_f32_32x32x16_f16(va[t * 2 + 0], bf0, o[qg][t], 0, 0, 0);
            o[qg][t] = __builtin_amdgcn_mfma_f32_32x32x16_f16(va[t * 2 + 1], bf1, o[qg][t], 0, 0, 0);
        }
        __builtin_amdgcn_s_setprio(0);
    }
}

__global__ __launch_bounds__(256, 2)
void flash_kernel(const short* __restrict__ qws, const short* __restrict__ kws,
                  const short* __restrict__ vws, float* __restrict__ out)
{
    __shared__ __align__(16) float olds[4 * 32 * OTS];   // 18432 B (epilogue only)

    const int tid  = threadIdx.x;
    const int wave = tid >> 6;
    const int lane = tid & 63;
    const int m32  = lane & 31;
    const int lh   = lane >> 5;          // lane-half
    const int koff = lh * 8;
    const int bh   = blockIdx.x;                     // XCD = bh % 8
    const int q0   = blockIdx.y * 256 + wave * 64;   // 64 q-rows per wave

    const short* qbase = qws + (size_t)bh * S_ * D_;
    const short* kfb   = kws + (size_t)bh * (S_ * 64);   // frag-major tiles
    const short* vfb   = vws + (size_t)bh * (S_ * 64);
    const int loff = lh * 256 + m32 * 8;                 // lane part of frag addr

    // Q^T B-frags (held): qb[qg][h]: B[d=h*16+lh*8+j][q=m32]
    f16x8 qb[2][4];
    #pragma unroll
    for (int qg = 0; qg < 2; ++qg)
        #pragma unroll
        for (int h = 0; h < 4; ++h)
            qb[qg][h] = *(const f16x8*)(qbase + (q0 + qg * 32 + m32) * D_ + h * 16 + koff);

    f32x16 z16;
    #pragma unroll
    for (int r = 0; r < 16; ++r) z16[r] = 0.f;

    f32x16 o[2][2];      // [qg][d-tile] O^T accumulators
    float  pl[2] = {0.f, 0.f};
    #pragma unroll
    for (int qg = 0; qg < 2; ++qg)
        #pragma unroll
        for (int t = 0; t < 2; ++t)
            o[qg][t] = z16;

    // frag loads: 8 contiguous 1KB wave-loads per tile, direct from global
    #define LOADFRAGS(T, kf, va) do {                                        \
        const short* kp_ = kfb + (size_t)(T) * 2048 + loff;                  \
        const short* vp_ = vfb + (size_t)(T) * 2048 + loff;                  \
        kf[0] = *(const f16x8*)(kp_);                                        \
        kf[1] = *(const f16x8*)(kp_ + 512);                                  \
        kf[2] = *(const f16x8*)(kp_ + 1024);                                 \
        kf[3] = *(const f16x8*)(kp_ + 1536);                                 \
        va[0] = *(const f16x8*)(vp_);                                        \
        va[1] = *(const f16x8*)(vp_ + 512);                                  \
        va[2] = *(const f16x8*)(vp_ + 1024);                                 \
        va[3] = *(const f16x8*)(vp_ + 1536);                                 \
    } while (0)

    f16x8 kfA[4], vaA[4], kfB[4], vaB[4];
    LOADFRAGS(0, kfA, vaA);

    for (int it = 0; it < 64; it += 2) {
        LOADFRAGS(it + 1, kfB, vaB);             // it+1 <= 63 always
        flash_compute(kfA, vaA, qb, z16, o, pl);
        if (it + 2 < 64)
            LOADFRAGS(it + 2, kfA, vaA);
        flash_compute(kfB, vaB, qb, z16, o, pl);
    }
    #undef LOADFRAGS

    // epilogue: complete row sums across lane-halves, normalize, transpose
    // O^T -> O one 32-wide d-tile at a time through per-wave LDS (32x36 f32,
    // per-wave region — no cross-wave hazard, no barrier), coalesced stores.
    const int b = bh >> 3, h = bh & 7;
    float* ow = olds + wave * (32 * OTS);
    #pragma unroll
    for (int qg = 0; qg < 2; ++qg) {
        float rs = pl[qg] + __shfl_xor(pl[qg], 32);
        float rl = 1.0f / rs;
        #pragma unroll
        for (int t = 0; t < 2; ++t) {
            const f32x16& ot = o[qg][t];
            #pragma unroll
            for (int g = 0; g < 4; ++g) {
                f32x4 w;
                w[0] = ot[g * 4 + 0] * rl;
                w[1] = ot[g * 4 + 1] * rl;
                w[2] = ot[g * 4 + 2] * rl;
                w[3] = ot[g * 4 + 3] * rl;
                // element (q=m32, dcol=r+8g+4lh) of this 32-wide d-tile
                *(f32x4*)(ow + m32 * OTS + 8 * g + 4 * lh) = w;
            }
            #pragma unroll
            for (int c = 0; c < 4; ++c) {
                const int row = (lane >> 3) + 8 * c;       // q-row within 32-row group
                f32x4 v = *(const f32x4*)(ow + row * OTS + (lane & 7) * 4);
                const int sq = q0 + qg * 32 + row;
                *(f32x4*)(out + ((size_t)(b * S_ + sq)) * DPROJ_
                              + h * 64 + t * 32 + (lane & 7) * 4) = v;
            }
        }
    }
}

// ---------------------------------------------------------------------------
extern "C" void kernel_launch(void* const* d_in, const int* in_sizes, int n_in,
                              void* d_out, int out_size, void* d_ws, size_t ws_size,
                              hipStream_t stream)
{
    const float* query = (const float*)d_in[0];
    const float* key   = (const float*)d_in[1];
    const float* value = (const float*)d_in[2];
    // d_in[3] = mask (int32) -- only its shape feeds the reference; unused.
    const float* Wq = (const float*)d_in[4];
    const float* bq = (const float*)d_in[5];
    const float* Wk = (const float*)d_in[6];
    const float* bk = (const float*)d_in[7];
    const float* Wv = (const float*)d_in[8];
    const float* bv = (const float*)d_in[9];

    float* out = (float*)d_out;
    short* ws  = (short*)d_ws;
    const size_t TSZ = (size_t)BH_ * S_ * D_;
    short* qws = ws;
    short* kws = ws + TSZ;
    short* vws = ws + 2 * TSZ;

    proj_kernel<<<dim3((B_ * S_) / 16, 3), 256, 0, stream>>>(
        query, key, value, Wq, bq, Wk, bk, Wv, bv, qws, kws, vws);
    flash_kernel<<<dim3(BH_, S_ / 256), 256, 0, stream>>>(qws, kws, vws, out);
}